// Round 2
// baseline (72048.462 us; speedup 1.0000x reference)
//
#include <hip/hip_runtime.h>

// Weight-resident VAE-LSTM: 256 blocks x 512 threads, 1 block/CU.
// Each block owns 8 hidden units; all 4 gate rows per unit resident as
// packed bf16 in 192 VGPRs/thread + 128KB LDS/block. Weights loaded once
// per section (enc, then dec); per-step traffic is activations only.
//
// R2 fix: __launch_bounds__(512,2) was interpreted as 2 BLOCKS/CU -> 128-VGPR
// budget -> wv[] spilled to scratch (VGPR_Count=128, FETCH unchanged, 72ms).
// Pin occupancy with amdgpu_waves_per_eu(2,2): 2 waves/SIMD = one 512-thread
// block per CU = 256-VGPR budget, enough for 192 resident + ~40 working.

#define NB 256
#define NT 512
#define HD 2048
#define TS 512

struct Params {
  const float* features;
  const float* eps;
  const float* Wih0e; const float* Whh0e;
  const float* Wih1e; const float* Whh1e;
  const float* Wmu;   const float* Wvar;
  const float* Wih0d; const float* Whh0d;
  const float* Wih1d; const float* Whh1d;
  const float* Wout;
  const float* bih0e; const float* bhh0e;
  const float* bih1e; const float* bhh1e;
  const float* bmu;   const float* bvar;
  const float* bih0d; const float* bhh0d;
  const float* bih1d; const float* bhh1d;
  const float* bout;
  float* out;
  float* act;
  unsigned* ctrl;
};

__device__ __forceinline__ unsigned pk(float lo, float hi) {
  unsigned a = __float_as_uint(lo), b = __float_as_uint(hi);
  a = (a + 0x7FFFu + ((a >> 16) & 1u)) >> 16;   // RNE to bf16
  b = (b + 0x7FFFu + ((b >> 16) & 1u)) >> 16;
  return a | (b << 16);
}
__device__ __forceinline__ float2 up(unsigned u) {
  float2 r;
  r.x = __uint_as_float(u << 16);
  r.y = __uint_as_float(u & 0xFFFF0000u);
  return r;
}
__device__ __forceinline__ float wred(float v) {
  v += __shfl_xor(v, 1);  v += __shfl_xor(v, 2);  v += __shfl_xor(v, 4);
  v += __shfl_xor(v, 8);  v += __shfl_xor(v, 16); v += __shfl_xor(v, 32);
  return v;
}
__device__ __forceinline__ float sigm(float x) { return 1.f / (1.f + __expf(-x)); }

__device__ __forceinline__ unsigned ld_rlx(unsigned* p) {
  return __hip_atomic_load(p, __ATOMIC_RELAXED, __HIP_MEMORY_SCOPE_AGENT);
}
__device__ __forceinline__ unsigned ld_acq(unsigned* p) {
  return __hip_atomic_load(p, __ATOMIC_ACQUIRE, __HIP_MEMORY_SCOPE_AGENT);
}
__device__ __forceinline__ void st_rel(unsigned* p, unsigned v) {
  __hip_atomic_store(p, v, __ATOMIC_RELEASE, __HIP_MEMORY_SCOPE_AGENT);
}

// All-sweep grid barrier: every block release-stores its own flag (64B slot),
// every block sweeps all NB flags with relaxed polls; one acquire per passage
// does the cache invalidate.
__device__ __forceinline__ void gbar(unsigned* ctrl, unsigned target) {
  __syncthreads();
  if (threadIdx.x == 0) st_rel(ctrl + (size_t)(1 + blockIdx.x) * 16, target);
  bool done = false;
  while (!done) {
    bool mine = true;
    if (threadIdx.x < NB)
      mine = (ld_rlx(ctrl + (size_t)(1 + threadIdx.x) * 16) >= target);
    done = (bool)__syncthreads_and((int)mine);
  }
  if (threadIdx.x == 0) (void)ld_acq(ctrl);
  __syncthreads();
}

// Load 4 gate-rows (wv rows RR0..RR0+3) of fp32 matrix W (K cols) for unit u,
// packing to bf16: CV column-blocks (of 256) into VGPRs at pk-offset O,
// CL trailing column-blocks into LDS (slot group M: 0=ih, 1=hh).
template<int RR0, int CV, int CL, int O, int M>
__device__ __forceinline__ void loadmat(unsigned (&wv)[8][24], unsigned (*lw)[NT],
                                        const float* __restrict__ W, int K,
                                        int u, int lane, int tid) {
#pragma unroll
  for (int q = 0; q < 4; ++q) {
    const float* rp = W + (size_t)(q * HD + u) * K + 4 * lane;
#pragma unroll
    for (int cb = 0; cb < CV; ++cb) {
      float4 f = *(const float4*)(rp + cb * 256);
      wv[RR0 + q][O + 2 * cb]     = pk(f.x, f.y);
      wv[RR0 + q][O + 2 * cb + 1] = pk(f.z, f.w);
    }
#pragma unroll
    for (int j = 0; j < CL; ++j) {
      float4 f = *(const float4*)(rp + (CV + j) * 256);
      lw[(RR0 + q) * 8 + M * 4 + 2 * j][tid]     = pk(f.x, f.y);
      lw[(RR0 + q) * 8 + M * 4 + 2 * j + 1][tid] = pk(f.z, f.w);
    }
  }
}

// One LSTM gate-matvec for 4 resident rows: x part = XV VGPR cbs + XL LDS cbs
// (pk-offset XO), h part = 6 VGPR cbs (pk-offset HO) + 2 LDS cbs.
template<int RR0, int XV, int XL, int XO, int HO>
__device__ __forceinline__ void cell4(const unsigned (&wv)[8][24],
                                      const unsigned (*lw)[NT],
                                      const float* __restrict__ xs,
                                      const float* __restrict__ hs,
                                      int lane, int tid, float* g) {
  float a0 = 0.f, a1 = 0.f, a2 = 0.f, a3 = 0.f;
#pragma unroll
  for (int cb = 0; cb < XV + XL; ++cb) {
    float4 xv = *(const float4*)(xs + cb * 256 + 4 * lane);
    unsigned u0, u1, u2, u3, u4, u5, u6, u7;
    if (cb < XV) {
      u0 = wv[RR0 + 0][XO + 2 * cb]; u1 = wv[RR0 + 0][XO + 2 * cb + 1];
      u2 = wv[RR0 + 1][XO + 2 * cb]; u3 = wv[RR0 + 1][XO + 2 * cb + 1];
      u4 = wv[RR0 + 2][XO + 2 * cb]; u5 = wv[RR0 + 2][XO + 2 * cb + 1];
      u6 = wv[RR0 + 3][XO + 2 * cb]; u7 = wv[RR0 + 3][XO + 2 * cb + 1];
    } else {
      const int j = cb - XV;
      u0 = lw[(RR0 + 0) * 8 + 2 * j][tid]; u1 = lw[(RR0 + 0) * 8 + 2 * j + 1][tid];
      u2 = lw[(RR0 + 1) * 8 + 2 * j][tid]; u3 = lw[(RR0 + 1) * 8 + 2 * j + 1][tid];
      u4 = lw[(RR0 + 2) * 8 + 2 * j][tid]; u5 = lw[(RR0 + 2) * 8 + 2 * j + 1][tid];
      u6 = lw[(RR0 + 3) * 8 + 2 * j][tid]; u7 = lw[(RR0 + 3) * 8 + 2 * j + 1][tid];
    }
    float2 p0 = up(u0), p1 = up(u1), p2 = up(u2), p3 = up(u3);
    float2 p4 = up(u4), p5 = up(u5), p6 = up(u6), p7 = up(u7);
    a0 = fmaf(p0.x, xv.x, a0); a0 = fmaf(p0.y, xv.y, a0);
    a0 = fmaf(p1.x, xv.z, a0); a0 = fmaf(p1.y, xv.w, a0);
    a1 = fmaf(p2.x, xv.x, a1); a1 = fmaf(p2.y, xv.y, a1);
    a1 = fmaf(p3.x, xv.z, a1); a1 = fmaf(p3.y, xv.w, a1);
    a2 = fmaf(p4.x, xv.x, a2); a2 = fmaf(p4.y, xv.y, a2);
    a2 = fmaf(p5.x, xv.z, a2); a2 = fmaf(p5.y, xv.w, a2);
    a3 = fmaf(p6.x, xv.x, a3); a3 = fmaf(p6.y, xv.y, a3);
    a3 = fmaf(p7.x, xv.z, a3); a3 = fmaf(p7.y, xv.w, a3);
  }
#pragma unroll
  for (int cb = 0; cb < 8; ++cb) {
    float4 hv = *(const float4*)(hs + cb * 256 + 4 * lane);
    unsigned u0, u1, u2, u3, u4, u5, u6, u7;
    if (cb < 6) {
      u0 = wv[RR0 + 0][HO + 2 * cb]; u1 = wv[RR0 + 0][HO + 2 * cb + 1];
      u2 = wv[RR0 + 1][HO + 2 * cb]; u3 = wv[RR0 + 1][HO + 2 * cb + 1];
      u4 = wv[RR0 + 2][HO + 2 * cb]; u5 = wv[RR0 + 2][HO + 2 * cb + 1];
      u6 = wv[RR0 + 3][HO + 2 * cb]; u7 = wv[RR0 + 3][HO + 2 * cb + 1];
    } else {
      const int j = cb - 6;
      u0 = lw[(RR0 + 0) * 8 + 4 + 2 * j][tid]; u1 = lw[(RR0 + 0) * 8 + 4 + 2 * j + 1][tid];
      u2 = lw[(RR0 + 1) * 8 + 4 + 2 * j][tid]; u3 = lw[(RR0 + 1) * 8 + 4 + 2 * j + 1][tid];
      u4 = lw[(RR0 + 2) * 8 + 4 + 2 * j][tid]; u5 = lw[(RR0 + 2) * 8 + 4 + 2 * j + 1][tid];
      u6 = lw[(RR0 + 3) * 8 + 4 + 2 * j][tid]; u7 = lw[(RR0 + 3) * 8 + 4 + 2 * j + 1][tid];
    }
    float2 p0 = up(u0), p1 = up(u1), p2 = up(u2), p3 = up(u3);
    float2 p4 = up(u4), p5 = up(u5), p6 = up(u6), p7 = up(u7);
    a0 = fmaf(p0.x, hv.x, a0); a0 = fmaf(p0.y, hv.y, a0);
    a0 = fmaf(p1.x, hv.z, a0); a0 = fmaf(p1.y, hv.w, a0);
    a1 = fmaf(p2.x, hv.x, a1); a1 = fmaf(p2.y, hv.y, a1);
    a1 = fmaf(p3.x, hv.z, a1); a1 = fmaf(p3.y, hv.w, a1);
    a2 = fmaf(p4.x, hv.x, a2); a2 = fmaf(p4.y, hv.y, a2);
    a2 = fmaf(p5.x, hv.z, a2); a2 = fmaf(p5.y, hv.w, a2);
    a3 = fmaf(p6.x, hv.x, a3); a3 = fmaf(p6.y, hv.y, a3);
    a3 = fmaf(p7.x, hv.z, a3); a3 = fmaf(p7.y, hv.w, a3);
  }
  g[0] = wred(a0); g[1] = wred(a1); g[2] = wred(a2); g[3] = wred(a3);
}

__device__ __forceinline__ void fuse(const float* g, const float* __restrict__ bih,
                                     const float* __restrict__ bhh, int u,
                                     float& c, float* hdst, int lane) {
  float gi = g[0] + bih[u]        + bhh[u];
  float gf = g[1] + bih[2048 + u] + bhh[2048 + u];
  float gc = g[2] + bih[4096 + u] + bhh[4096 + u];
  float go = g[3] + bih[6144 + u] + bhh[6144 + u];
  float cn = sigm(gf) * c + sigm(gi) * tanhf(gc);
  c = cn;
  if (lane == 0) hdst[u] = sigm(go) * tanhf(cn);
}

__global__ void init_kernel(unsigned* ctrl) {
  for (int i = threadIdx.x; i < (1 + NB) * 16; i += 256) ctrl[i] = 0u;
}

__global__ __launch_bounds__(NT)
__attribute__((amdgpu_flat_work_group_size(NT, NT), amdgpu_waves_per_eu(2, 2)))
void vae_kernel(Params p) {
  __shared__ unsigned lw[64][NT];   // 128 KB resident weight LDS (per-thread columns)
  __shared__ float st[2 * HD];      // 16 KB staging: stx | sth
  float* stx = st;
  float* sth = st + HD;

  const int tid = threadIdx.x;
  const int wave = tid >> 6, lane = tid & 63;
  const int b = blockIdx.x;
  const int u = b * 8 + wave;       // owned hidden unit
  unsigned* ctrl = p.ctrl;
  float* act = p.act;
  float* h0b  = act;                // [2][2048] parity
  float* h1b  = act + 4096;
  float* dh0b = act + 8192;
  float* dh1b = act + 12288;
  float* mub  = act + 16384;        // 4096
  float* spb  = act + 20480;        // 4096
  unsigned gf = 0;
  float g[4];

  unsigned wv[8][24];               // 192 packed-bf16 VGPRs of resident weights
  float c0 = 0.f, c1 = 0.f;         // cell states live in registers end-to-end

  // ---- encoder resident load (fp32 -> packed bf16, once) ----
  loadmat<0, 4, 0, 0, 0>(wv, lw, p.Wih0e, 1024, u, lane, tid);  // rows 0-3: L0
  loadmat<0, 6, 2, 8, 1>(wv, lw, p.Whh0e, 2048, u, lane, tid);
  loadmat<4, 6, 2, 0, 0>(wv, lw, p.Wih1e, 2048, u, lane, tid);  // rows 4-7: L1
  loadmat<4, 6, 2, 12, 1>(wv, lw, p.Whh1e, 2048, u, lane, tid);

  // ---- encoder: 512 steps x 2 phases ----
  for (int t = 0; t < TS; ++t) {
    // phase 0: layer0, x = features[t] (1024), h = h0[t-1]
    if (tid < 256)
      *(float4*)(stx + tid * 4) = *(const float4*)(p.features + (size_t)t * 1024 + tid * 4);
    if (t == 0) {
      float4 z; z.x = 0.f; z.y = 0.f; z.z = 0.f; z.w = 0.f;
      *(float4*)(sth + tid * 4) = z;
    } else {
      *(float4*)(sth + tid * 4) = *(const float4*)(h0b + (t & 1) * HD + tid * 4);
    }
    __syncthreads();
    cell4<0, 4, 0, 0, 8>(wv, lw, stx, sth, lane, tid, g);
    fuse(g, p.bih0e, p.bhh0e, u, c0, h0b + ((t + 1) & 1) * HD, lane);
    gbar(ctrl, ++gf);

    // phase 1: layer1, x = h0[t] (fresh), h = h1[t-1]
    *(float4*)(stx + tid * 4) = *(const float4*)(h0b + ((t + 1) & 1) * HD + tid * 4);
    if (t == 0) {
      float4 z; z.x = 0.f; z.y = 0.f; z.z = 0.f; z.w = 0.f;
      *(float4*)(sth + tid * 4) = z;
    } else {
      *(float4*)(sth + tid * 4) = *(const float4*)(h1b + (t & 1) * HD + tid * 4);
    }
    __syncthreads();
    cell4<4, 6, 2, 0, 12>(wv, lw, stx, sth, lane, tid, g);
    fuse(g, p.bih1e, p.bhh1e, u, c1, h1b + ((t + 1) & 1) * HD, lane);
    gbar(ctrl, ++gf);
  }

  // ---- latent: mu / log(softplus(var)) from h0_last (h0b[0]) & h1_last (h1b[0]) ----
  {
    *(float4*)(stx + tid * 4) = *(const float4*)(h0b + tid * 4);
    *(float4*)(sth + tid * 4) = *(const float4*)(h1b + tid * 4);
    __syncthreads();
    const bool isVar = (b >= 128);
    const int r0 = (b & 127) * 16 + wave * 2;
    const float* Wl = isVar ? p.Wvar : p.Wmu;
    const float* rp0 = Wl + (size_t)r0 * HD + 4 * lane;
    const float* rp1 = rp0 + HD;
    float a00 = 0.f, a01 = 0.f, a10 = 0.f, a11 = 0.f;
#pragma unroll
    for (int cb = 0; cb < 8; ++cb) {
      float4 w0 = *(const float4*)(rp0 + cb * 256);
      float4 w1 = *(const float4*)(rp1 + cb * 256);
      float4 xv = *(const float4*)(stx + cb * 256 + 4 * lane);
      float4 hv = *(const float4*)(sth + cb * 256 + 4 * lane);
      a00 = fmaf(w0.x, xv.x, fmaf(w0.y, xv.y, fmaf(w0.z, xv.z, fmaf(w0.w, xv.w, a00))));
      a01 = fmaf(w0.x, hv.x, fmaf(w0.y, hv.y, fmaf(w0.z, hv.z, fmaf(w0.w, hv.w, a01))));
      a10 = fmaf(w1.x, xv.x, fmaf(w1.y, xv.y, fmaf(w1.z, xv.z, fmaf(w1.w, xv.w, a10))));
      a11 = fmaf(w1.x, hv.x, fmaf(w1.y, hv.y, fmaf(w1.z, hv.z, fmaf(w1.w, hv.w, a11))));
    }
    a00 = wred(a00); a01 = wred(a01); a10 = wred(a10); a11 = wred(a11);
    if (lane == 0) {
#pragma unroll
      for (int r = 0; r < 2; ++r) {
        const int i = r0 + r;
        const float vx = r ? a10 : a00;   // from h0 -> s=0
        const float vh = r ? a11 : a01;   // from h1 -> s=1
        if (!isVar) {
          float m0 = vx + p.bmu[i], m1 = vh + p.bmu[i];
          p.out[i] = m0;        mub[i] = m0;
          p.out[HD + i] = m1;   mub[HD + i] = m1;
        } else {
          float v0 = vx + p.bvar[i], v1 = vh + p.bvar[i];
          float s0 = (v0 > 15.f) ? v0 : log1pf(__expf(v0));
          float s1 = (v1 > 15.f) ? v1 : log1pf(__expf(v1));
          p.out[4096 + i] = __logf(s0);      spb[i] = s0;
          p.out[4096 + HD + i] = __logf(s1); spb[HD + i] = s1;
        }
      }
    }
  }
  gbar(ctrl, ++gf);

  // ---- decoder resident load (overwrites wv/lw; lw columns are thread-private) ----
  loadmat<0, 6, 2, 0, 0>(wv, lw, p.Wih0d, 2048, u, lane, tid);   // rows 0-3: L0
  loadmat<0, 6, 2, 12, 1>(wv, lw, p.Whh0d, 2048, u, lane, tid);
  loadmat<4, 6, 2, 0, 0>(wv, lw, p.Wih1d, 2048, u, lane, tid);   // rows 4-7: L1
  loadmat<4, 6, 2, 12, 1>(wv, lw, p.Whh1d, 2048, u, lane, tid);

  // ---- decoder: 512 steps x 2 phases; Wout (fp32, L2-resident) fused in phase 0 ----
  for (int t = 0; t < TS; ++t) {
    // phase 0: layer0, x = dh1[t-1] (t=0: zeros), h = dh0[t-1] (t=0: z[0])
    if (t == 0) {
      float4 z; z.x = 0.f; z.y = 0.f; z.z = 0.f; z.w = 0.f;
      *(float4*)(stx + tid * 4) = z;
      float4 m = *(const float4*)(mub + tid * 4);
      float4 e = *(const float4*)(p.eps + tid * 4);
      float4 s = *(const float4*)(spb + tid * 4);
      float4 zv;
      zv.x = m.x + e.x * sqrtf(s.x); zv.y = m.y + e.y * sqrtf(s.y);
      zv.z = m.z + e.z * sqrtf(s.z); zv.w = m.w + e.w * sqrtf(s.w);
      *(float4*)(sth + tid * 4) = zv;
    } else {
      *(float4*)(stx + tid * 4) = *(const float4*)(dh1b + (t & 1) * HD + tid * 4);
      *(float4*)(sth + tid * 4) = *(const float4*)(dh0b + (t & 1) * HD + tid * 4);
    }
    __syncthreads();
    cell4<0, 6, 2, 0, 12>(wv, lw, stx, sth, lane, tid, g);
    fuse(g, p.bih0d, p.bhh0d, u, c0, dh0b + ((t + 1) & 1) * HD, lane);
    if (t > 0 && wave < 4) {   // out_{t-1} = Wout @ dh1[t-1] (stx), fp32 weights
      const int orow = b * 4 + wave;
      const float* wr = p.Wout + (size_t)orow * HD + 4 * lane;
      float a = 0.f;
#pragma unroll
      for (int cb = 0; cb < 8; ++cb) {
        float4 w4v = *(const float4*)(wr + cb * 256);
        float4 xv = *(const float4*)(stx + cb * 256 + 4 * lane);
        a = fmaf(w4v.x, xv.x, fmaf(w4v.y, xv.y, fmaf(w4v.z, xv.z, fmaf(w4v.w, xv.w, a))));
      }
      a = wred(a);
      if (lane == 0) p.out[8192 + (size_t)(512 - t) * 1024 + orow] = a + p.bout[orow];
    }
    gbar(ctrl, ++gf);

    // phase 1: layer1, x = dh0[t] (fresh -> sth), h = dh1[t-1] (kept in stx; t=0: z[1])
    *(float4*)(sth + tid * 4) = *(const float4*)(dh0b + ((t + 1) & 1) * HD + tid * 4);
    if (t == 0) {
      float4 m = *(const float4*)(mub + HD + tid * 4);
      float4 e = *(const float4*)(p.eps + HD + tid * 4);
      float4 s = *(const float4*)(spb + HD + tid * 4);
      float4 zv;
      zv.x = m.x + e.x * sqrtf(s.x); zv.y = m.y + e.y * sqrtf(s.y);
      zv.z = m.z + e.z * sqrtf(s.z); zv.w = m.w + e.w * sqrtf(s.w);
      *(float4*)(stx + tid * 4) = zv;
    }
    __syncthreads();
    cell4<4, 6, 2, 0, 12>(wv, lw, sth, stx, lane, tid, g);   // xs=dh0_new, hs=dh1_prev
    fuse(g, p.bih1d, p.bhh1d, u, c1, dh1b + ((t + 1) & 1) * HD, lane);
    gbar(ctrl, ++gf);
  }

  // ---- final out_511 -> decoded[0]; x = dh1[511] = dh1b[0] ----
  *(float4*)(stx + tid * 4) = *(const float4*)(dh1b + tid * 4);
  __syncthreads();
  if (wave < 4) {
    const int orow = b * 4 + wave;
    const float* wr = p.Wout + (size_t)orow * HD + 4 * lane;
    float a = 0.f;
#pragma unroll
    for (int cb = 0; cb < 8; ++cb) {
      float4 w4v = *(const float4*)(wr + cb * 256);
      float4 xv = *(const float4*)(stx + cb * 256 + 4 * lane);
      a = fmaf(w4v.x, xv.x, fmaf(w4v.y, xv.y, fmaf(w4v.z, xv.z, fmaf(w4v.w, xv.w, a))));
    }
    a = wred(a);
    if (lane == 0) p.out[8192 + orow] = a + p.bout[orow];
  }
}

extern "C" void kernel_launch(void* const* d_in, const int* in_sizes, int n_in,
                              void* d_out, int out_size, void* d_ws, size_t ws_size,
                              hipStream_t stream) {
  (void)in_sizes; (void)n_in; (void)out_size; (void)ws_size;
  Params p;
  p.features = (const float*)d_in[0];
  p.eps      = (const float*)d_in[1];
  p.Wih0e = (const float*)d_in[2];  p.Whh0e = (const float*)d_in[3];
  p.bih0e = (const float*)d_in[4];  p.bhh0e = (const float*)d_in[5];
  p.Wih1e = (const float*)d_in[6];  p.Whh1e = (const float*)d_in[7];
  p.bih1e = (const float*)d_in[8];  p.bhh1e = (const float*)d_in[9];
  p.Wmu   = (const float*)d_in[10]; p.bmu   = (const float*)d_in[11];
  p.Wvar  = (const float*)d_in[12]; p.bvar  = (const float*)d_in[13];
  p.Wih0d = (const float*)d_in[14]; p.Whh0d = (const float*)d_in[15];
  p.bih0d = (const float*)d_in[16]; p.bhh0d = (const float*)d_in[17];
  p.Wih1d = (const float*)d_in[18]; p.Whh1d = (const float*)d_in[19];
  p.bih1d = (const float*)d_in[20]; p.bhh1d = (const float*)d_in[21];
  p.Wout  = (const float*)d_in[22]; p.bout  = (const float*)d_in[23];
  p.out = (float*)d_out;

  char* ws = (char*)d_ws;
  p.ctrl = (unsigned*)ws;                 // (1+NB)*64 = 16448 bytes
  p.act  = (float*)(ws + 32768);          // 24576 floats

  init_kernel<<<dim3(1), dim3(256), 0, stream>>>(p.ctrl);
  void* args[] = { &p };
  hipLaunchCooperativeKernel(reinterpret_cast<void*>(vae_kernel),
                             dim3(NB), dim3(NT), args, 0, stream);
}

// Round 4
// 70001.447 us; speedup vs baseline: 1.0292x; 1.0292x over previous
//
#include <hip/hip_runtime.h>
#include <utility>

// Weight-resident VAE-LSTM: 256 blocks x 512 threads, 1 block/CU.
// Each block owns 8 hidden units; 4 gate rows per unit resident as packed
// bf16 in 192 VGPRs/thread (24 named uv8 vectors) + 128KB LDS/block.
// R3: wv[8][24] alloca never SROA-promoted -> scratch (R1/R2: FETCH ~62GB,
// VGPR=128). R4: named ext-vectors accessed via FREE function templates
// (getw/setw) -- avoids both the alloca and dependent-template syntax.

#define NB 256
#define NT 512
#define HD 2048
#define TS 512

typedef unsigned uv8 __attribute__((ext_vector_type(8)));

template<typename F, int... Is>
__device__ __forceinline__ void unroll_i(F&& f, std::integer_sequence<int, Is...>) {
  (f(std::integral_constant<int, Is>{}), ...);
}
template<int N, typename F>
__device__ __forceinline__ void unrollN(F&& f) {
  unroll_i(f, std::make_integer_sequence<int, N>{});
}

// One resident gate-row: 24 packed-bf16 u32 = 3 named uv8 vectors.
struct W24 { uv8 a, b, c; };
// 8 resident rows (4 gates x 2 layers for this thread's wave-owned unit).
struct WRegs { W24 r0, r1, r2, r3, r4, r5, r6, r7; };

template<int R> __device__ __forceinline__ W24& rowref(WRegs& w) {
  if constexpr (R == 0) return w.r0;
  else if constexpr (R == 1) return w.r1;
  else if constexpr (R == 2) return w.r2;
  else if constexpr (R == 3) return w.r3;
  else if constexpr (R == 4) return w.r4;
  else if constexpr (R == 5) return w.r5;
  else if constexpr (R == 6) return w.r6;
  else return w.r7;
}
template<int R, int J> __device__ __forceinline__ unsigned getw(WRegs& w) {
  W24& r = rowref<R>(w);
  if constexpr (J < 8) return r.a[J];
  else if constexpr (J < 16) return r.b[J - 8];
  else return r.c[J - 16];
}
template<int R, int J> __device__ __forceinline__ void setw(WRegs& w, unsigned v) {
  W24& r = rowref<R>(w);
  if constexpr (J < 8) r.a[J] = v;
  else if constexpr (J < 16) r.b[J - 8] = v;
  else r.c[J - 16] = v;
}

struct Params {
  const float* features;
  const float* eps;
  const float* Wih0e; const float* Whh0e;
  const float* Wih1e; const float* Whh1e;
  const float* Wmu;   const float* Wvar;
  const float* Wih0d; const float* Whh0d;
  const float* Wih1d; const float* Whh1d;
  const float* Wout;
  const float* bih0e; const float* bhh0e;
  const float* bih1e; const float* bhh1e;
  const float* bmu;   const float* bvar;
  const float* bih0d; const float* bhh0d;
  const float* bih1d; const float* bhh1d;
  const float* bout;
  float* out;
  float* act;
  unsigned* ctrl;
};

__device__ __forceinline__ unsigned pk(float lo, float hi) {
  unsigned a = __float_as_uint(lo), b = __float_as_uint(hi);
  a = (a + 0x7FFFu + ((a >> 16) & 1u)) >> 16;   // RNE to bf16
  b = (b + 0x7FFFu + ((b >> 16) & 1u)) >> 16;
  return a | (b << 16);
}
__device__ __forceinline__ float2 up(unsigned u) {
  float2 r;
  r.x = __uint_as_float(u << 16);
  r.y = __uint_as_float(u & 0xFFFF0000u);
  return r;
}
__device__ __forceinline__ float wred(float v) {
  v += __shfl_xor(v, 1);  v += __shfl_xor(v, 2);  v += __shfl_xor(v, 4);
  v += __shfl_xor(v, 8);  v += __shfl_xor(v, 16); v += __shfl_xor(v, 32);
  return v;
}
__device__ __forceinline__ float sigm(float x) { return 1.f / (1.f + __expf(-x)); }

__device__ __forceinline__ unsigned ld_rlx(unsigned* p) {
  return __hip_atomic_load(p, __ATOMIC_RELAXED, __HIP_MEMORY_SCOPE_AGENT);
}
__device__ __forceinline__ unsigned ld_acq(unsigned* p) {
  return __hip_atomic_load(p, __ATOMIC_ACQUIRE, __HIP_MEMORY_SCOPE_AGENT);
}
__device__ __forceinline__ void st_rel(unsigned* p, unsigned v) {
  __hip_atomic_store(p, v, __ATOMIC_RELEASE, __HIP_MEMORY_SCOPE_AGENT);
}

// All-sweep grid barrier (validated R1/R2): every block release-stores its
// flag, all blocks sweep all NB flags with relaxed polls, one acquire per
// passage does the cache invalidate.
__device__ __forceinline__ void gbar(unsigned* ctrl, unsigned target) {
  __syncthreads();
  if (threadIdx.x == 0) st_rel(ctrl + (size_t)(1 + blockIdx.x) * 16, target);
  bool done = false;
  while (!done) {
    bool mine = true;
    if (threadIdx.x < NB)
      mine = (ld_rlx(ctrl + (size_t)(1 + threadIdx.x) * 16) >= target);
    done = (bool)__syncthreads_and((int)mine);
  }
  if (threadIdx.x == 0) (void)ld_acq(ctrl);
  __syncthreads();
}

// Load 4 gate-rows (rows RR0..RR0+3) of fp32 matrix W (K cols) for unit u,
// packing to bf16: CV column-blocks (of 256) into VGPRs at u32-offset O,
// CL trailing column-blocks into LDS (slot group M: 0=ih, 1=hh).
// Each thread writes only its own lw column [tid] (no cross-thread sharing).
template<int RR0, int CV, int CL, int O, int M>
__device__ __forceinline__ void loadmat(WRegs& w, unsigned (*lw)[NT],
                                        const float* __restrict__ W, int K,
                                        int u, int lane, int tid) {
  unrollN<4>([&](auto Q) {
    constexpr int q = decltype(Q)::value;
    const float* rp = W + (size_t)(q * HD + u) * K + 4 * lane;
    unrollN<CV>([&](auto CB) {
      constexpr int cb = decltype(CB)::value;
      float4 fv = *(const float4*)(rp + cb * 256);
      setw<RR0 + q, O + 2 * cb>(w, pk(fv.x, fv.y));
      setw<RR0 + q, O + 2 * cb + 1>(w, pk(fv.z, fv.w));
    });
    unrollN<CL>([&](auto J) {
      constexpr int j = decltype(J)::value;
      float4 fv = *(const float4*)(rp + (CV + j) * 256);
      lw[(RR0 + q) * 8 + M * 4 + 2 * j][tid]     = pk(fv.x, fv.y);
      lw[(RR0 + q) * 8 + M * 4 + 2 * j + 1][tid] = pk(fv.z, fv.w);
    });
  });
}

// One LSTM gate-matvec for 4 resident rows: x part = XV VGPR cbs + XL LDS
// cbs (u32-offset XO), h part = 6 VGPR cbs (u32-offset HO) + 2 LDS cbs.
// FMA order identical to the validated R1/R2 kernel.
template<int RR0, int XV, int XL, int XO, int HO>
__device__ __forceinline__ void cell4(WRegs& w, const unsigned (*lw)[NT],
                                      const float* __restrict__ xs,
                                      const float* __restrict__ hs,
                                      int lane, int tid,
                                      float& g0, float& g1, float& g2, float& g3) {
  float a0 = 0.f, a1 = 0.f, a2 = 0.f, a3 = 0.f;
  unrollN<XV + XL>([&](auto CB) {
    constexpr int cb = decltype(CB)::value;
    float4 xv = *(const float4*)(xs + cb * 256 + 4 * lane);
    unsigned u0, u1, u2, u3, u4, u5, u6, u7;
    if constexpr (cb < XV) {
      u0 = getw<RR0 + 0, XO + 2 * cb>(w); u1 = getw<RR0 + 0, XO + 2 * cb + 1>(w);
      u2 = getw<RR0 + 1, XO + 2 * cb>(w); u3 = getw<RR0 + 1, XO + 2 * cb + 1>(w);
      u4 = getw<RR0 + 2, XO + 2 * cb>(w); u5 = getw<RR0 + 2, XO + 2 * cb + 1>(w);
      u6 = getw<RR0 + 3, XO + 2 * cb>(w); u7 = getw<RR0 + 3, XO + 2 * cb + 1>(w);
    } else {
      constexpr int j = (cb - XV >= 0) ? (cb - XV) : 0;
      u0 = lw[(RR0 + 0) * 8 + 2 * j][tid]; u1 = lw[(RR0 + 0) * 8 + 2 * j + 1][tid];
      u2 = lw[(RR0 + 1) * 8 + 2 * j][tid]; u3 = lw[(RR0 + 1) * 8 + 2 * j + 1][tid];
      u4 = lw[(RR0 + 2) * 8 + 2 * j][tid]; u5 = lw[(RR0 + 2) * 8 + 2 * j + 1][tid];
      u6 = lw[(RR0 + 3) * 8 + 2 * j][tid]; u7 = lw[(RR0 + 3) * 8 + 2 * j + 1][tid];
    }
    float2 p0 = up(u0), p1 = up(u1), p2 = up(u2), p3 = up(u3);
    float2 p4 = up(u4), p5 = up(u5), p6 = up(u6), p7 = up(u7);
    a0 = fmaf(p0.x, xv.x, a0); a0 = fmaf(p0.y, xv.y, a0);
    a0 = fmaf(p1.x, xv.z, a0); a0 = fmaf(p1.y, xv.w, a0);
    a1 = fmaf(p2.x, xv.x, a1); a1 = fmaf(p2.y, xv.y, a1);
    a1 = fmaf(p3.x, xv.z, a1); a1 = fmaf(p3.y, xv.w, a1);
    a2 = fmaf(p4.x, xv.x, a2); a2 = fmaf(p4.y, xv.y, a2);
    a2 = fmaf(p5.x, xv.z, a2); a2 = fmaf(p5.y, xv.w, a2);
    a3 = fmaf(p6.x, xv.x, a3); a3 = fmaf(p6.y, xv.y, a3);
    a3 = fmaf(p7.x, xv.z, a3); a3 = fmaf(p7.y, xv.w, a3);
  });
  unrollN<8>([&](auto CB) {
    constexpr int cb = decltype(CB)::value;
    float4 hv = *(const float4*)(hs + cb * 256 + 4 * lane);
    unsigned u0, u1, u2, u3, u4, u5, u6, u7;
    if constexpr (cb < 6) {
      u0 = getw<RR0 + 0, HO + 2 * cb>(w); u1 = getw<RR0 + 0, HO + 2 * cb + 1>(w);
      u2 = getw<RR0 + 1, HO + 2 * cb>(w); u3 = getw<RR0 + 1, HO + 2 * cb + 1>(w);
      u4 = getw<RR0 + 2, HO + 2 * cb>(w); u5 = getw<RR0 + 2, HO + 2 * cb + 1>(w);
      u6 = getw<RR0 + 3, HO + 2 * cb>(w); u7 = getw<RR0 + 3, HO + 2 * cb + 1>(w);
    } else {
      constexpr int j = (cb - 6 >= 0) ? (cb - 6) : 0;
      u0 = lw[(RR0 + 0) * 8 + 4 + 2 * j][tid]; u1 = lw[(RR0 + 0) * 8 + 4 + 2 * j + 1][tid];
      u2 = lw[(RR0 + 1) * 8 + 4 + 2 * j][tid]; u3 = lw[(RR0 + 1) * 8 + 4 + 2 * j + 1][tid];
      u4 = lw[(RR0 + 2) * 8 + 4 + 2 * j][tid]; u5 = lw[(RR0 + 2) * 8 + 4 + 2 * j + 1][tid];
      u6 = lw[(RR0 + 3) * 8 + 4 + 2 * j][tid]; u7 = lw[(RR0 + 3) * 8 + 4 + 2 * j + 1][tid];
    }
    float2 p0 = up(u0), p1 = up(u1), p2 = up(u2), p3 = up(u3);
    float2 p4 = up(u4), p5 = up(u5), p6 = up(u6), p7 = up(u7);
    a0 = fmaf(p0.x, hv.x, a0); a0 = fmaf(p0.y, hv.y, a0);
    a0 = fmaf(p1.x, hv.z, a0); a0 = fmaf(p1.y, hv.w, a0);
    a1 = fmaf(p2.x, hv.x, a1); a1 = fmaf(p2.y, hv.y, a1);
    a1 = fmaf(p3.x, hv.z, a1); a1 = fmaf(p3.y, hv.w, a1);
    a2 = fmaf(p4.x, hv.x, a2); a2 = fmaf(p4.y, hv.y, a2);
    a2 = fmaf(p5.x, hv.z, a2); a2 = fmaf(p5.y, hv.w, a2);
    a3 = fmaf(p6.x, hv.x, a3); a3 = fmaf(p6.y, hv.y, a3);
    a3 = fmaf(p7.x, hv.z, a3); a3 = fmaf(p7.y, hv.w, a3);
  });
  g0 = wred(a0); g1 = wred(a1); g2 = wred(a2); g3 = wred(a3);
}

__device__ __forceinline__ void fuse(float g0, float g1, float g2, float g3,
                                     const float* __restrict__ bih,
                                     const float* __restrict__ bhh, int u,
                                     float& c, float* hdst, int lane) {
  float gi = g0 + bih[u]        + bhh[u];
  float gf = g1 + bih[2048 + u] + bhh[2048 + u];
  float gc = g2 + bih[4096 + u] + bhh[4096 + u];
  float go = g3 + bih[6144 + u] + bhh[6144 + u];
  float cn = sigm(gf) * c + sigm(gi) * tanhf(gc);
  c = cn;
  if (lane == 0) hdst[u] = sigm(go) * tanhf(cn);
}

__global__ void init_kernel(unsigned* ctrl) {
  for (int i = threadIdx.x; i < (1 + NB) * 16; i += 256) ctrl[i] = 0u;
}

__global__ __attribute__((amdgpu_flat_work_group_size(NT, NT), amdgpu_waves_per_eu(2, 2)))
void vae_kernel(Params p) {
  __shared__ unsigned lw[64][NT];   // 128 KB resident weight LDS (per-thread columns)
  __shared__ float st[2 * HD];      // 16 KB staging: stx | sth
  float* stx = st;
  float* sth = st + HD;

  const int tid = threadIdx.x;
  const int wave = tid >> 6, lane = tid & 63;
  const int b = blockIdx.x;
  const int u = b * 8 + wave;       // owned hidden unit
  unsigned* ctrl = p.ctrl;
  float* act = p.act;
  float* h0b  = act;                // [2][2048] parity
  float* h1b  = act + 4096;
  float* dh0b = act + 8192;
  float* dh1b = act + 12288;
  float* mub  = act + 16384;        // 4096
  float* spb  = act + 20480;        // 4096
  unsigned gf = 0;
  float g0, g1, g2, g3;

  WRegs w;                          // 192 packed-bf16 u32 in named vectors
  float c0 = 0.f, c1 = 0.f;         // cell states live in registers end-to-end

  // ---- encoder resident load (fp32 -> packed bf16, once) ----
  loadmat<0, 4, 0, 0, 0>(w, lw, p.Wih0e, 1024, u, lane, tid);   // rows 0-3: L0
  loadmat<0, 6, 2, 8, 1>(w, lw, p.Whh0e, 2048, u, lane, tid);
  loadmat<4, 6, 2, 0, 0>(w, lw, p.Wih1e, 2048, u, lane, tid);   // rows 4-7: L1
  loadmat<4, 6, 2, 12, 1>(w, lw, p.Whh1e, 2048, u, lane, tid);

  // ---- encoder: 512 steps x 2 phases ----
  for (int t = 0; t < TS; ++t) {
    // phase 0: layer0, x = features[t] (1024), h = h0[t-1]
    if (tid < 256)
      *(float4*)(stx + tid * 4) = *(const float4*)(p.features + (size_t)t * 1024 + tid * 4);
    if (t == 0) {
      float4 z; z.x = 0.f; z.y = 0.f; z.z = 0.f; z.w = 0.f;
      *(float4*)(sth + tid * 4) = z;
    } else {
      *(float4*)(sth + tid * 4) = *(const float4*)(h0b + (t & 1) * HD + tid * 4);
    }
    __syncthreads();
    cell4<0, 4, 0, 0, 8>(w, lw, stx, sth, lane, tid, g0, g1, g2, g3);
    fuse(g0, g1, g2, g3, p.bih0e, p.bhh0e, u, c0, h0b + ((t + 1) & 1) * HD, lane);
    gbar(ctrl, ++gf);

    // phase 1: layer1, x = h0[t] (fresh), h = h1[t-1]
    *(float4*)(stx + tid * 4) = *(const float4*)(h0b + ((t + 1) & 1) * HD + tid * 4);
    if (t == 0) {
      float4 z; z.x = 0.f; z.y = 0.f; z.z = 0.f; z.w = 0.f;
      *(float4*)(sth + tid * 4) = z;
    } else {
      *(float4*)(sth + tid * 4) = *(const float4*)(h1b + (t & 1) * HD + tid * 4);
    }
    __syncthreads();
    cell4<4, 6, 2, 0, 12>(w, lw, stx, sth, lane, tid, g0, g1, g2, g3);
    fuse(g0, g1, g2, g3, p.bih1e, p.bhh1e, u, c1, h1b + ((t + 1) & 1) * HD, lane);
    gbar(ctrl, ++gf);
  }

  // ---- latent: mu / log(softplus(var)) from h0_last (h0b[0]) & h1_last (h1b[0]) ----
  {
    *(float4*)(stx + tid * 4) = *(const float4*)(h0b + tid * 4);
    *(float4*)(sth + tid * 4) = *(const float4*)(h1b + tid * 4);
    __syncthreads();
    const bool isVar = (b >= 128);
    const int r0 = (b & 127) * 16 + wave * 2;
    const float* Wl = isVar ? p.Wvar : p.Wmu;
    const float* rp0 = Wl + (size_t)r0 * HD + 4 * lane;
    const float* rp1 = rp0 + HD;
    float a00 = 0.f, a01 = 0.f, a10 = 0.f, a11 = 0.f;
#pragma unroll
    for (int cb = 0; cb < 8; ++cb) {
      float4 w0 = *(const float4*)(rp0 + cb * 256);
      float4 w1 = *(const float4*)(rp1 + cb * 256);
      float4 xv = *(const float4*)(stx + cb * 256 + 4 * lane);
      float4 hv = *(const float4*)(sth + cb * 256 + 4 * lane);
      a00 = fmaf(w0.x, xv.x, fmaf(w0.y, xv.y, fmaf(w0.z, xv.z, fmaf(w0.w, xv.w, a00))));
      a01 = fmaf(w0.x, hv.x, fmaf(w0.y, hv.y, fmaf(w0.z, hv.z, fmaf(w0.w, hv.w, a01))));
      a10 = fmaf(w1.x, xv.x, fmaf(w1.y, xv.y, fmaf(w1.z, xv.z, fmaf(w1.w, xv.w, a10))));
      a11 = fmaf(w1.x, hv.x, fmaf(w1.y, hv.y, fmaf(w1.z, hv.z, fmaf(w1.w, hv.w, a11))));
    }
    a00 = wred(a00); a01 = wred(a01); a10 = wred(a10); a11 = wred(a11);
    if (lane == 0) {
#pragma unroll
      for (int r = 0; r < 2; ++r) {
        const int i = r0 + r;
        const float vx = r ? a10 : a00;   // from h0 -> s=0
        const float vh = r ? a11 : a01;   // from h1 -> s=1
        if (!isVar) {
          float m0 = vx + p.bmu[i], m1 = vh + p.bmu[i];
          p.out[i] = m0;        mub[i] = m0;
          p.out[HD + i] = m1;   mub[HD + i] = m1;
        } else {
          float v0 = vx + p.bvar[i], v1 = vh + p.bvar[i];
          float s0 = (v0 > 15.f) ? v0 : log1pf(__expf(v0));
          float s1 = (v1 > 15.f) ? v1 : log1pf(__expf(v1));
          p.out[4096 + i] = __logf(s0);      spb[i] = s0;
          p.out[4096 + HD + i] = __logf(s1); spb[HD + i] = s1;
        }
      }
    }
  }
  gbar(ctrl, ++gf);

  // ---- decoder resident load (overwrites w/lw; lw columns are thread-private) ----
  loadmat<0, 6, 2, 0, 0>(w, lw, p.Wih0d, 2048, u, lane, tid);    // rows 0-3: L0
  loadmat<0, 6, 2, 12, 1>(w, lw, p.Whh0d, 2048, u, lane, tid);
  loadmat<4, 6, 2, 0, 0>(w, lw, p.Wih1d, 2048, u, lane, tid);    // rows 4-7: L1
  loadmat<4, 6, 2, 12, 1>(w, lw, p.Whh1d, 2048, u, lane, tid);

  // ---- decoder: 512 steps x 2 phases; Wout (fp32, L2-resident) fused in phase 0 ----
  for (int t = 0; t < TS; ++t) {
    // phase 0: layer0, x = dh1[t-1] (t=0: zeros), h = dh0[t-1] (t=0: z[0])
    if (t == 0) {
      float4 z; z.x = 0.f; z.y = 0.f; z.z = 0.f; z.w = 0.f;
      *(float4*)(stx + tid * 4) = z;
      float4 m = *(const float4*)(mub + tid * 4);
      float4 e = *(const float4*)(p.eps + tid * 4);
      float4 s = *(const float4*)(spb + tid * 4);
      float4 zv;
      zv.x = m.x + e.x * sqrtf(s.x); zv.y = m.y + e.y * sqrtf(s.y);
      zv.z = m.z + e.z * sqrtf(s.z); zv.w = m.w + e.w * sqrtf(s.w);
      *(float4*)(sth + tid * 4) = zv;
    } else {
      *(float4*)(stx + tid * 4) = *(const float4*)(dh1b + (t & 1) * HD + tid * 4);
      *(float4*)(sth + tid * 4) = *(const float4*)(dh0b + (t & 1) * HD + tid * 4);
    }
    __syncthreads();
    cell4<0, 6, 2, 0, 12>(w, lw, stx, sth, lane, tid, g0, g1, g2, g3);
    fuse(g0, g1, g2, g3, p.bih0d, p.bhh0d, u, c0, dh0b + ((t + 1) & 1) * HD, lane);
    if (t > 0 && wave < 4) {   // out_{t-1} = Wout @ dh1[t-1] (stx), fp32 weights
      const int orow = b * 4 + wave;
      const float* wr = p.Wout + (size_t)orow * HD + 4 * lane;
      float a = 0.f;
#pragma unroll
      for (int cb = 0; cb < 8; ++cb) {
        float4 w4v = *(const float4*)(wr + cb * 256);
        float4 xv = *(const float4*)(stx + cb * 256 + 4 * lane);
        a = fmaf(w4v.x, xv.x, fmaf(w4v.y, xv.y, fmaf(w4v.z, xv.z, fmaf(w4v.w, xv.w, a))));
      }
      a = wred(a);
      if (lane == 0) p.out[8192 + (size_t)(512 - t) * 1024 + orow] = a + p.bout[orow];
    }
    gbar(ctrl, ++gf);

    // phase 1: layer1, x = dh0[t] (fresh -> sth), h = dh1[t-1] (kept in stx; t=0: z[1])
    *(float4*)(sth + tid * 4) = *(const float4*)(dh0b + ((t + 1) & 1) * HD + tid * 4);
    if (t == 0) {
      float4 m = *(const float4*)(mub + HD + tid * 4);
      float4 e = *(const float4*)(p.eps + HD + tid * 4);
      float4 s = *(const float4*)(spb + HD + tid * 4);
      float4 zv;
      zv.x = m.x + e.x * sqrtf(s.x); zv.y = m.y + e.y * sqrtf(s.y);
      zv.z = m.z + e.z * sqrtf(s.z); zv.w = m.w + e.w * sqrtf(s.w);
      *(float4*)(stx + tid * 4) = zv;
    }
    __syncthreads();
    cell4<4, 6, 2, 0, 12>(w, lw, sth, stx, lane, tid, g0, g1, g2, g3);  // xs=dh0_new, hs=dh1_prev
    fuse(g0, g1, g2, g3, p.bih1d, p.bhh1d, u, c1, dh1b + ((t + 1) & 1) * HD, lane);
    gbar(ctrl, ++gf);
  }

  // ---- final out_511 -> decoded[0]; x = dh1[511] = dh1b[0] ----
  *(float4*)(stx + tid * 4) = *(const float4*)(dh1b + tid * 4);
  __syncthreads();
  if (wave < 4) {
    const int orow = b * 4 + wave;
    const float* wr = p.Wout + (size_t)orow * HD + 4 * lane;
    float a = 0.f;
#pragma unroll
    for (int cb = 0; cb < 8; ++cb) {
      float4 w4v = *(const float4*)(wr + cb * 256);
      float4 xv = *(const float4*)(stx + cb * 256 + 4 * lane);
      a = fmaf(w4v.x, xv.x, fmaf(w4v.y, xv.y, fmaf(w4v.z, xv.z, fmaf(w4v.w, xv.w, a))));
    }
    a = wred(a);
    if (lane == 0) p.out[8192 + orow] = a + p.bout[orow];
  }
}

extern "C" void kernel_launch(void* const* d_in, const int* in_sizes, int n_in,
                              void* d_out, int out_size, void* d_ws, size_t ws_size,
                              hipStream_t stream) {
  (void)in_sizes; (void)n_in; (void)out_size; (void)ws_size;
  Params p;
  p.features = (const float*)d_in[0];
  p.eps      = (const float*)d_in[1];
  p.Wih0e = (const float*)d_in[2];  p.Whh0e = (const float*)d_in[3];
  p.bih0e = (const float*)d_in[4];  p.bhh0e = (const float*)d_in[5];
  p.Wih1e = (const float*)d_in[6];  p.Whh1e = (const float*)d_in[7];
  p.bih1e = (const float*)d_in[8];  p.bhh1e = (const float*)d_in[9];
  p.Wmu   = (const float*)d_in[10]; p.bmu   = (const float*)d_in[11];
  p.Wvar  = (const float*)d_in[12]; p.bvar  = (const float*)d_in[13];
  p.Wih0d = (const float*)d_in[14]; p.Whh0d = (const float*)d_in[15];
  p.bih0d = (const float*)d_in[16]; p.bhh0d = (const float*)d_in[17];
  p.Wih1d = (const float*)d_in[18]; p.Whh1d = (const float*)d_in[19];
  p.bih1d = (const float*)d_in[20]; p.bhh1d = (const float*)d_in[21];
  p.Wout  = (const float*)d_in[22]; p.bout  = (const float*)d_in[23];
  p.out = (float*)d_out;

  char* ws = (char*)d_ws;
  p.ctrl = (unsigned*)ws;                 // (1+NB)*64 = 16448 bytes
  p.act  = (float*)(ws + 32768);          // 24576 floats

  init_kernel<<<dim3(1), dim3(256), 0, stream>>>(p.ctrl);
  void* args[] = { &p };
  hipLaunchCooperativeKernel(reinterpret_cast<void*>(vae_kernel),
                             dim3(NB), dim3(NT), args, 0, stream);
}